// Round 5
// baseline (4982.861 us; speedup 1.0000x reference)
//
#include <hip/hip_runtime.h>
#include <hip/hip_fp16.h>

#define B_ 256
#define S_ 512
#define D_ 200
#define H_ 256

typedef _Float16 half2_t __attribute__((ext_vector_type(2)));
typedef _Float16 half8_t __attribute__((ext_vector_type(8)));
typedef float    floatx4 __attribute__((ext_vector_type(4)));

__device__ __forceinline__ float fast_sig(float x) {
    return 1.f / (1.f + __expf(-x));
}
__device__ __forceinline__ float fast_tanh(float x) {
    x = fminf(15.f, fmaxf(-15.f, x));
    float e = __expf(2.f * x);
    return (e - 1.f) / (e + 1.f);
}

// ---------------------------------------------------------------------------
// prep: build fp16 weight layouts in workspace.
//   W4T [1024][224]: W4T[n][k] = Wg[k][j] (x-part rows 0..199, zero-padded)
//   WhT [1024][256]: WhT[n][k] = Wg[200+k][j] (h-part), n = g*256+j
// ---------------------------------------------------------------------------
__global__ void prep(const float* __restrict__ Wi, const float* __restrict__ Wf,
                     const float* __restrict__ Wo, const float* __restrict__ Wz,
                     _Float16* __restrict__ W4T, _Float16* __restrict__ WhT) {
    const int n = blockIdx.x;      // 0..1023
    const int t = threadIdx.x;     // 0..255
    const int g = n >> 8, j = n & 255;
    const float* Wg = (g == 0) ? Wi : (g == 1) ? Wf : (g == 2) ? Wo : Wz;
    if (t < 224)
        W4T[(size_t)n * 224 + t] = (t < D_) ? (_Float16)Wg[t * 256 + j] : (_Float16)0.f;
    WhT[(size_t)n * 256 + t] = (_Float16)Wg[(D_ + t) * 256 + j];
}

// ---------------------------------------------------------------------------
// gemm_x: preact_x[m][n] = sum_k X[m][k]*W4T[n][k] + bias[n]
// Output written into G2 in the EXACT MFMA-C-fragment layout the recurrence
// consumes:  G2[b][w][quad][s][mi][r]  (halfs),
//   n = g*256 + (2w+jbh)*16 + quad*4 + r,  mi = jbh*4 + g,  b,s from m.
// ---------------------------------------------------------------------------
__global__ __launch_bounds__(256) void gemm_x(const float* __restrict__ X,
                                              const _Float16* __restrict__ W4T,
                                              const float* __restrict__ bi,
                                              const float* __restrict__ bfg,
                                              const float* __restrict__ bo,
                                              const float* __restrict__ bz,
                                              _Float16* __restrict__ G2) {
    __shared__ __align__(16) _Float16 As[128][40];
    __shared__ __align__(16) _Float16 Bs[128][40];

    const int mt = blockIdx.x >> 3;
    const int nt = blockIdx.x & 7;
    const int m0 = mt * 128, n0 = nt * 128;
    const int tid  = threadIdx.x;
    const int lane = tid & 63, wave = tid >> 6;
    const int quad = lane >> 4, l16 = lane & 15;
    const int mq = (wave & 1) * 64, nq = (wave >> 1) * 64;

    floatx4 acc[4][4];
#pragma unroll
    for (int i = 0; i < 4; ++i)
#pragma unroll
        for (int j = 0; j < 4; ++j) acc[i][j] = (floatx4){0.f, 0.f, 0.f, 0.f};

    const int srow = tid >> 1;
    const int koff = (tid & 1) * 16;

    for (int kt = 0; kt < 7; ++kt) {
        const int k0 = kt * 32;
        {
            const int m = m0 + srow;
            const float* xr = X + (size_t)m * D_ + (k0 + koff);
            half8_t v0, v1;
            if (m < B_ * S_ - 1) {
                const floatx4* xp = (const floatx4*)xr;
                floatx4 f0 = xp[0], f1 = xp[1], f2 = xp[2], f3 = xp[3];
#pragma unroll
                for (int i = 0; i < 4; ++i) {
                    v0[i]     = (_Float16)f0[i];
                    v0[4 + i] = (_Float16)f1[i];
                    v1[i]     = (_Float16)f2[i];
                    v1[4 + i] = (_Float16)f3[i];
                }
            } else {
#pragma unroll
                for (int i = 0; i < 8; ++i) {
                    int k = k0 + koff + i;
                    v0[i] = (k < D_) ? (_Float16)xr[i] : (_Float16)0.f;
                }
#pragma unroll
                for (int i = 0; i < 8; ++i) {
                    int k = k0 + koff + 8 + i;
                    v1[i] = (k < D_) ? (_Float16)xr[8 + i] : (_Float16)0.f;
                }
            }
            *(half8_t*)&As[srow][koff]     = v0;
            *(half8_t*)&As[srow][koff + 8] = v1;
        }
        {
            const _Float16* wr = W4T + (size_t)(n0 + srow) * 224 + (k0 + koff);
            const half8_t* wp = (const half8_t*)wr;
            *(half8_t*)&Bs[srow][koff]     = wp[0];
            *(half8_t*)&Bs[srow][koff + 8] = wp[1];
        }
        __syncthreads();

        half8_t af[4], bf[4];
#pragma unroll
        for (int i = 0; i < 4; ++i) af[i] = *(const half8_t*)&As[mq + i * 16 + l16][quad * 8];
#pragma unroll
        for (int i = 0; i < 4; ++i) bf[i] = *(const half8_t*)&Bs[nq + i * 16 + l16][quad * 8];
#pragma unroll
        for (int mi = 0; mi < 4; ++mi)
#pragma unroll
            for (int ni = 0; ni < 4; ++ni)
                acc[mi][ni] = __builtin_amdgcn_mfma_f32_16x16x32_f16(af[mi], bf[ni], acc[mi][ni], 0, 0, 0);
        __syncthreads();
    }

    // ---- epilogue: scatter into G2 fragment layout (+bias) ----
    // C/D layout: grow = m0+mq+mi_g*16+quad*4+r (the X row = b*512+s),
    //             gcol = n0+nq+ni*16+l16.
    // bb is constant per block (m-tile of 128 never crosses a b boundary).
    const int bb = m0 >> 9;
    const int sbase0 = (m0 & 511) + mq + quad * 4;   // ss = sbase0 + mi_g*16 + r
#pragma unroll
    for (int ni = 0; ni < 4; ++ni) {
        const int gcol = n0 + nq + ni * 16 + l16;
        const int g = gcol >> 8, j = gcol & 255;
        const int jb = j >> 4, wv = jb >> 1, jbh = jb & 1;
        const int mi2 = jbh * 4 + g, q2 = (j >> 2) & 3, r2 = j & 3;
        const float bv = ((g == 0) ? bi : (g == 1) ? bfg : (g == 2) ? bo : bz)[j];
        const size_t base = ((((size_t)bb * 8 + wv) * 4 + q2) * 512 + sbase0) * 32
                            + (size_t)mi2 * 4 + r2;
#pragma unroll
        for (int mi = 0; mi < 4; ++mi)
#pragma unroll
            for (int r = 0; r < 4; ++r)
                G2[base + (size_t)(mi * 16 + r) * 32] = (_Float16)(acc[mi][ni][r] + bv);
    }
}

// ---------------------------------------------------------------------------
// lstm_rec: one workgroup (512 threads = 8 waves) per batch row.
// MFMA recurrence: D = Wh^T (A, register-resident) x h (B, LDS broadcast) + G.
// Wave w owns gate-cols [32w, 32w+32) for all 4 gates (8 M-tiles, mi=jbh*4+g).
// B-frag read address is l16-independent -> all 16 N-lanes get the same h ->
// D is valid (replicated) in every lane; lane (l16, quad) owns the c/h state
// for j = 32w + jbh_c*16 + quad*4 + r_c with jbh_c=(l16>>2)&1, r_c=l16&3.
// h double-buffered in LDS -> ONE barrier per step.
// ---------------------------------------------------------------------------
__global__ __launch_bounds__(512, 1) void lstm_rec(
    const _Float16* __restrict__ G2,    // fragment layout, fp16, bias folded
    const _Float16* __restrict__ WhT,   // [1024][256] fp16
    const float* __restrict__ mask,     // [B][S] fp32
    float* __restrict__ out)            // [B][256] fp32
{
    __shared__ __align__(16) _Float16 hS[2][256];

    const int b    = blockIdx.x;
    const int t    = threadIdx.x;   // 0..511
    const int w    = t >> 6;        // wave 0..7
    const int lane = t & 63;
    const int l16  = lane & 15, quad = lane >> 4;

    // ---- A fragments (weights), 64 x half8 = 256 VGPRs, pinned ----
    half8_t A[8][8];
#pragma unroll
    for (int mi = 0; mi < 8; ++mi) {
        const int g = mi & 3, jbh = mi >> 2;
        const int gcol = g * 256 + (2 * w + jbh) * 16 + l16;
        const _Float16* wp = WhT + (size_t)gcol * 256 + quad * 8;
#pragma unroll
        for (int kt = 0; kt < 8; ++kt) {
            A[mi][kt] = *(const half8_t*)(wp + kt * 32);
            asm volatile("" : "+v"(A[mi][kt]));
        }
    }

    // G2 slice for (b, w, quad): per-step stride = 32 halfs = 4 half8
    const half8_t* Gp = (const half8_t*)(G2 + (((size_t)b * 8 + w) * 4 + quad) * 512 * 32);

    if (t < 256) hS[0][t] = (_Float16)0.f;

    const int jbh_c = (l16 >> 2) & 1;
    const int r_c   = l16 & 3;
    const int j     = 32 * w + jbh_c * 16 + quad * 4 + r_c;

    float cst = 0.f, accum = 0.f, msum = 0.f;
    const float* mb = mask + (size_t)b * S_;

    half8_t Gcur[4];
#pragma unroll
    for (int p = 0; p < 4; ++p) Gcur[p] = Gp[p];

    __syncthreads();

    for (int s = 0; s < S_; ++s) {
        const float m = mb[s];

        // B fragments: wave-uniform-per-quad LDS broadcast of h
        const _Float16* hb = hS[s & 1];
        half8_t Bf[8];
#pragma unroll
        for (int kt = 0; kt < 8; ++kt)
            Bf[kt] = *(const half8_t*)(hb + kt * 32 + quad * 8);

        // C init from prefetched G (preacts incl. bias, fp16 -> fp32)
        floatx4 C[8];
#pragma unroll
        for (int p = 0; p < 4; ++p) {
#pragma unroll
            for (int k = 0; k < 4; ++k) {
                C[2 * p][k]     = (float)Gcur[p][k];
                C[2 * p + 1][k] = (float)Gcur[p][4 + k];
            }
        }
        // prefetch next step's G
        if (s + 1 < S_) {
#pragma unroll
            for (int p = 0; p < 4; ++p) Gcur[p] = Gp[(size_t)(s + 1) * 4 + p];
        }

        // recurrence MFMA: C += Wh^T * h
#pragma unroll
        for (int kt = 0; kt < 8; ++kt)
#pragma unroll
            for (int mi = 0; mi < 8; ++mi)
                C[mi] = __builtin_amdgcn_mfma_f32_16x16x32_f16(A[mi][kt], Bf[kt], C[mi], 0, 0, 0);

        // gate select: pre_g = C[jbh_c*4 + g][r_c]
        float pre[4];
#pragma unroll
        for (int g = 0; g < 4; ++g) {
            floatx4 cg = jbh_c ? C[4 + g] : C[g];
            const float v01 = (r_c & 1) ? cg[1] : cg[0];
            const float v23 = (r_c & 1) ? cg[3] : cg[2];
            pre[g] = (r_c & 2) ? v23 : v01;
        }
        const float fi = fast_sig(pre[0]);
        const float ff = fast_sig(pre[1]);
        const float fo = fast_sig(pre[2]);
        const float fz = fast_tanh(pre[3]);
        cst = fi * fz + ff * cst;
        const float h = fo * fast_tanh(cst);
        accum += m * h;
        msum  += m;
        if (l16 < 8) hS[(s + 1) & 1][j] = (_Float16)h;
        __syncthreads();
    }

    if (l16 < 8) out[b * 256 + j] = accum / msum;
}

extern "C" void kernel_launch(void* const* d_in, const int* in_sizes, int n_in,
                              void* d_out, int out_size, void* d_ws, size_t ws_size,
                              hipStream_t stream) {
    const float* X    = (const float*)d_in[0];
    const float* mask = (const float*)d_in[1];
    const float* Wi   = (const float*)d_in[2];
    const float* bi   = (const float*)d_in[3];
    const float* Wf   = (const float*)d_in[4];
    const float* bf   = (const float*)d_in[5];
    const float* Wo   = (const float*)d_in[6];
    const float* bo   = (const float*)d_in[7];
    const float* Wz   = (const float*)d_in[8];
    const float* bz   = (const float*)d_in[9];
    float* out = (float*)d_out;

    char* ws = (char*)d_ws;
    _Float16* G2  = (_Float16*)ws;                                   // 268,435,456 B
    _Float16* W4T = (_Float16*)(ws + (size_t)B_ * S_ * 1024 * 2);    //     458,752 B
    _Float16* WhT = (_Float16*)(ws + (size_t)B_ * S_ * 1024 * 2 + (size_t)1024 * 224 * 2);

    hipLaunchKernelGGL(prep,     dim3(1024), dim3(256), 0, stream, Wi, Wf, Wo, Wz, W4T, WhT);
    hipLaunchKernelGGL(gemm_x,   dim3(8192), dim3(256), 0, stream, X, W4T, bi, bf, bo, bz, G2);
    hipLaunchKernelGGL(lstm_rec, dim3(B_),   dim3(512), 0, stream, G2, WhT, mask, out);
}

// Round 6
// 1510.531 us; speedup vs baseline: 3.2987x; 3.2987x over previous
//
#include <hip/hip_runtime.h>
#include <hip/hip_fp16.h>

#define B_ 256
#define S_ 512
#define D_ 200
#define H_ 256

typedef _Float16 half2_t __attribute__((ext_vector_type(2)));
typedef _Float16 half8_t __attribute__((ext_vector_type(8)));
typedef float    floatx4 __attribute__((ext_vector_type(4)));

__device__ __forceinline__ float fast_sig(float x) {
    return 1.f / (1.f + __expf(-x));
}
__device__ __forceinline__ float fast_tanh(float x) {
    x = fminf(15.f, fmaxf(-15.f, x));
    float e = __expf(2.f * x);
    return (e - 1.f) / (e + 1.f);
}

// ---------------------------------------------------------------------------
// prep: build fp16 weight layouts in workspace.
//   W4T [1024][224]: W4T[n][k] = Wg[k][j] (x-part rows 0..199, zero-padded)
//   WhT [1024][256]: WhT[n][k] = Wg[200+k][j] (h-part), n = g*256+j
// ---------------------------------------------------------------------------
__global__ void prep(const float* __restrict__ Wi, const float* __restrict__ Wf,
                     const float* __restrict__ Wo, const float* __restrict__ Wz,
                     _Float16* __restrict__ W4T, _Float16* __restrict__ WhT) {
    const int n = blockIdx.x;      // 0..1023
    const int t = threadIdx.x;     // 0..255
    const int g = n >> 8, j = n & 255;
    const float* Wg = (g == 0) ? Wi : (g == 1) ? Wf : (g == 2) ? Wo : Wz;
    if (t < 224)
        W4T[(size_t)n * 224 + t] = (t < D_) ? (_Float16)Wg[t * 256 + j] : (_Float16)0.f;
    WhT[(size_t)n * 256 + t] = (_Float16)Wg[(D_ + t) * 256 + j];
}

// ---------------------------------------------------------------------------
// gemm_x: preact_x[m][n] = sum_k X[m][k]*W4T[n][k] + bias[n]
// Output written into G2 in the EXACT MFMA-C-fragment layout the recurrence
// consumes:  G2[b][w][quad][s][mi][r]  (halfs). Validated in round 5.
// ---------------------------------------------------------------------------
__global__ __launch_bounds__(256) void gemm_x(const float* __restrict__ X,
                                              const _Float16* __restrict__ W4T,
                                              const float* __restrict__ bi,
                                              const float* __restrict__ bfg,
                                              const float* __restrict__ bo,
                                              const float* __restrict__ bz,
                                              _Float16* __restrict__ G2) {
    __shared__ __align__(16) _Float16 As[128][40];
    __shared__ __align__(16) _Float16 Bs[128][40];

    const int mt = blockIdx.x >> 3;
    const int nt = blockIdx.x & 7;
    const int m0 = mt * 128, n0 = nt * 128;
    const int tid  = threadIdx.x;
    const int lane = tid & 63, wave = tid >> 6;
    const int quad = lane >> 4, l16 = lane & 15;
    const int mq = (wave & 1) * 64, nq = (wave >> 1) * 64;

    floatx4 acc[4][4];
#pragma unroll
    for (int i = 0; i < 4; ++i)
#pragma unroll
        for (int j = 0; j < 4; ++j) acc[i][j] = (floatx4){0.f, 0.f, 0.f, 0.f};

    const int srow = tid >> 1;
    const int koff = (tid & 1) * 16;

    for (int kt = 0; kt < 7; ++kt) {
        const int k0 = kt * 32;
        {
            const int m = m0 + srow;
            const float* xr = X + (size_t)m * D_ + (k0 + koff);
            half8_t v0, v1;
            if (m < B_ * S_ - 1) {
                const floatx4* xp = (const floatx4*)xr;
                floatx4 f0 = xp[0], f1 = xp[1], f2 = xp[2], f3 = xp[3];
#pragma unroll
                for (int i = 0; i < 4; ++i) {
                    v0[i]     = (_Float16)f0[i];
                    v0[4 + i] = (_Float16)f1[i];
                    v1[i]     = (_Float16)f2[i];
                    v1[4 + i] = (_Float16)f3[i];
                }
            } else {
#pragma unroll
                for (int i = 0; i < 8; ++i) {
                    int k = k0 + koff + i;
                    v0[i] = (k < D_) ? (_Float16)xr[i] : (_Float16)0.f;
                }
#pragma unroll
                for (int i = 0; i < 8; ++i) {
                    int k = k0 + koff + 8 + i;
                    v1[i] = (k < D_) ? (_Float16)xr[8 + i] : (_Float16)0.f;
                }
            }
            *(half8_t*)&As[srow][koff]     = v0;
            *(half8_t*)&As[srow][koff + 8] = v1;
        }
        {
            const _Float16* wr = W4T + (size_t)(n0 + srow) * 224 + (k0 + koff);
            const half8_t* wp = (const half8_t*)wr;
            *(half8_t*)&Bs[srow][koff]     = wp[0];
            *(half8_t*)&Bs[srow][koff + 8] = wp[1];
        }
        __syncthreads();

        half8_t af[4], bf[4];
#pragma unroll
        for (int i = 0; i < 4; ++i) af[i] = *(const half8_t*)&As[mq + i * 16 + l16][quad * 8];
#pragma unroll
        for (int i = 0; i < 4; ++i) bf[i] = *(const half8_t*)&Bs[nq + i * 16 + l16][quad * 8];
#pragma unroll
        for (int mi = 0; mi < 4; ++mi)
#pragma unroll
            for (int ni = 0; ni < 4; ++ni)
                acc[mi][ni] = __builtin_amdgcn_mfma_f32_16x16x32_f16(af[mi], bf[ni], acc[mi][ni], 0, 0, 0);
        __syncthreads();
    }

    const int bb = m0 >> 9;
    const int sbase0 = (m0 & 511) + mq + quad * 4;
#pragma unroll
    for (int ni = 0; ni < 4; ++ni) {
        const int gcol = n0 + nq + ni * 16 + l16;
        const int g = gcol >> 8, j = gcol & 255;
        const int jb = j >> 4, wv = jb >> 1, jbh = jb & 1;
        const int mi2 = jbh * 4 + g, q2 = (j >> 2) & 3, r2 = j & 3;
        const float bv = ((g == 0) ? bi : (g == 1) ? bfg : (g == 2) ? bo : bz)[j];
        const size_t base = ((((size_t)bb * 8 + wv) * 4 + q2) * 512 + sbase0) * 32
                            + (size_t)mi2 * 4 + r2;
#pragma unroll
        for (int mi = 0; mi < 4; ++mi)
#pragma unroll
            for (int r = 0; r < 4; ++r)
                G2[base + (size_t)(mi * 16 + r) * 32] = (_Float16)(acc[mi][ni][r] + bv);
    }
}

// ---------------------------------------------------------------------------
// lstm_rec: one workgroup (512 threads = 8 waves) per batch row.
// Same validated layout as round 5; register plan fixed for the 256-VGPR cap:
//   A k in [0,192): 48 NAMED pinned half8 vars (192 VGPRs).
//   A k in [192,256): LDS, pre-swizzled fragment order (lane-contiguous b128).
//   C: 8 named floatx4. G prefetch split 2+2. Peak ~250 regs.
// ---------------------------------------------------------------------------
__global__ __launch_bounds__(512, 2) void lstm_rec(
    const _Float16* __restrict__ G2,    // fragment layout, fp16, bias folded
    const _Float16* __restrict__ WhT,   // [1024][256] fp16
    const float* __restrict__ mask,     // [B][S] fp32
    float* __restrict__ out)            // [B][256] fp32
{
    __shared__ __align__(16) half8_t  WLfrag[8192];   // 128 KB: [(w*8+mi)*2+ktL][lane]
    __shared__ __align__(16) _Float16 hS[2][256];     // 1 KB

    const int b    = blockIdx.x;
    const int t    = threadIdx.x;   // 0..511
    const int w    = t >> 6;        // wave 0..7
    const int lane = t & 63;
    const int l16  = lane & 15, quad = lane >> 4;

    // ---- stage LDS A-fragments (k in [192,256)) in fragment order ----
#pragma unroll
    for (int mi = 0; mi < 8; ++mi) {
        const int gcol = ((mi & 3) << 8) + (2 * w + (mi >> 2)) * 16 + l16;
        const half8_t* src = (const half8_t*)(WhT + (size_t)gcol * 256);
        WLfrag[((w * 8 + mi) * 2 + 0) * 64 + lane] = src[6 * 4 + quad];
        WLfrag[((w * 8 + mi) * 2 + 1) * 64 + lane] = src[7 * 4 + quad];
    }

    // ---- register A-fragments: k in [0,192), 48 named pinned half8 ----
#define DECLF(mi) half8_t F##mi##_0, F##mi##_1, F##mi##_2, F##mi##_3, F##mi##_4, F##mi##_5
#define LOADF(mi) do {                                                        \
        const int gcol = ((mi & 3) << 8) + (2 * w + ((mi) >> 2)) * 16 + l16;  \
        const half8_t* p = (const half8_t*)(WhT + (size_t)gcol * 256);        \
        F##mi##_0 = p[0 * 4 + quad]; F##mi##_1 = p[1 * 4 + quad];             \
        F##mi##_2 = p[2 * 4 + quad]; F##mi##_3 = p[3 * 4 + quad];             \
        F##mi##_4 = p[4 * 4 + quad]; F##mi##_5 = p[5 * 4 + quad];             \
        asm volatile("" : "+v"(F##mi##_0), "+v"(F##mi##_1), "+v"(F##mi##_2),  \
                          "+v"(F##mi##_3), "+v"(F##mi##_4), "+v"(F##mi##_5)); \
    } while (0)
    DECLF(0); DECLF(1); DECLF(2); DECLF(3); DECLF(4); DECLF(5); DECLF(6); DECLF(7);
    LOADF(0); LOADF(1); LOADF(2); LOADF(3); LOADF(4); LOADF(5); LOADF(6); LOADF(7);

    // G2 slice for (b, w, quad): per-step stride = 4 half8
    const half8_t* Gp = (const half8_t*)(G2 + (((size_t)b * 8 + w) * 4 + quad) * 512 * 32);

    if (t < 256) hS[0][t] = (_Float16)0.f;

    const int jbh_c = (l16 >> 2) & 1;
    const int r_c   = l16 & 3;
    const int j     = 32 * w + jbh_c * 16 + quad * 4 + r_c;

    float cst = 0.f, accum = 0.f, msum = 0.f;
    const float* mb = mask + (size_t)b * S_;

    half8_t G0 = Gp[0], G1 = Gp[1], G2c = Gp[2], G3 = Gp[3];

    __syncthreads();

#define MFALL(kt, Bv)                                                          \
    C0 = __builtin_amdgcn_mfma_f32_16x16x32_f16(F0_##kt, Bv, C0, 0, 0, 0);     \
    C1 = __builtin_amdgcn_mfma_f32_16x16x32_f16(F1_##kt, Bv, C1, 0, 0, 0);     \
    C2 = __builtin_amdgcn_mfma_f32_16x16x32_f16(F2_##kt, Bv, C2, 0, 0, 0);     \
    C3 = __builtin_amdgcn_mfma_f32_16x16x32_f16(F3_##kt, Bv, C3, 0, 0, 0);     \
    C4 = __builtin_amdgcn_mfma_f32_16x16x32_f16(F4_##kt, Bv, C4, 0, 0, 0);     \
    C5 = __builtin_amdgcn_mfma_f32_16x16x32_f16(F5_##kt, Bv, C5, 0, 0, 0);     \
    C6 = __builtin_amdgcn_mfma_f32_16x16x32_f16(F6_##kt, Bv, C6, 0, 0, 0);     \
    C7 = __builtin_amdgcn_mfma_f32_16x16x32_f16(F7_##kt, Bv, C7, 0, 0, 0)

#define MFLDS(ktL, Bv)                                                         \
    C0 = __builtin_amdgcn_mfma_f32_16x16x32_f16(WLfrag[((w*8+0)*2+(ktL))*64+lane], Bv, C0, 0, 0, 0); \
    C1 = __builtin_amdgcn_mfma_f32_16x16x32_f16(WLfrag[((w*8+1)*2+(ktL))*64+lane], Bv, C1, 0, 0, 0); \
    C2 = __builtin_amdgcn_mfma_f32_16x16x32_f16(WLfrag[((w*8+2)*2+(ktL))*64+lane], Bv, C2, 0, 0, 0); \
    C3 = __builtin_amdgcn_mfma_f32_16x16x32_f16(WLfrag[((w*8+3)*2+(ktL))*64+lane], Bv, C3, 0, 0, 0); \
    C4 = __builtin_amdgcn_mfma_f32_16x16x32_f16(WLfrag[((w*8+4)*2+(ktL))*64+lane], Bv, C4, 0, 0, 0); \
    C5 = __builtin_amdgcn_mfma_f32_16x16x32_f16(WLfrag[((w*8+5)*2+(ktL))*64+lane], Bv, C5, 0, 0, 0); \
    C6 = __builtin_amdgcn_mfma_f32_16x16x32_f16(WLfrag[((w*8+6)*2+(ktL))*64+lane], Bv, C6, 0, 0, 0); \
    C7 = __builtin_amdgcn_mfma_f32_16x16x32_f16(WLfrag[((w*8+7)*2+(ktL))*64+lane], Bv, C7, 0, 0, 0)

    for (int s = 0; s < S_; ++s) {
        const float m = mb[s];
        const _Float16* hb = hS[s & 1];

        // C init from prefetched G (fp16 preacts incl. bias)
        floatx4 C0, C1, C2, C3, C4, C5, C6, C7;
#pragma unroll
        for (int k = 0; k < 4; ++k) {
            C0[k] = (float)G0[k];  C1[k] = (float)G0[4 + k];
            C2[k] = (float)G1[k];  C3[k] = (float)G1[4 + k];
            C4[k] = (float)G2c[k]; C5[k] = (float)G2c[4 + k];
            C6[k] = (float)G3[k];  C7[k] = (float)G3[4 + k];
        }
        const int sn = (s < S_ - 1) ? s + 1 : s;

        half8_t Bv;
        Bv = *(const half8_t*)(hb + 0 * 32 + quad * 8);  MFALL(0, Bv);
        G0 = Gp[(size_t)sn * 4 + 0]; G1 = Gp[(size_t)sn * 4 + 1];
        Bv = *(const half8_t*)(hb + 1 * 32 + quad * 8);  MFALL(1, Bv);
        Bv = *(const half8_t*)(hb + 2 * 32 + quad * 8);  MFALL(2, Bv);
        Bv = *(const half8_t*)(hb + 3 * 32 + quad * 8);  MFALL(3, Bv);
        G2c = Gp[(size_t)sn * 4 + 2]; G3 = Gp[(size_t)sn * 4 + 3];
        Bv = *(const half8_t*)(hb + 4 * 32 + quad * 8);  MFALL(4, Bv);
        Bv = *(const half8_t*)(hb + 5 * 32 + quad * 8);  MFALL(5, Bv);
        Bv = *(const half8_t*)(hb + 6 * 32 + quad * 8);  MFLDS(0, Bv);
        Bv = *(const half8_t*)(hb + 7 * 32 + quad * 8);  MFLDS(1, Bv);

        // gate select: pre_g = C[jbh_c*4 + g][r_c]
        floatx4 s0 = jbh_c ? C4 : C0;
        floatx4 s1 = jbh_c ? C5 : C1;
        floatx4 s2 = jbh_c ? C6 : C2;
        floatx4 s3 = jbh_c ? C7 : C3;
        float pre[4];
        {
            floatx4 cg = s0;
            float v01 = (r_c & 1) ? cg[1] : cg[0], v23 = (r_c & 1) ? cg[3] : cg[2];
            pre[0] = (r_c & 2) ? v23 : v01;
            cg = s1; v01 = (r_c & 1) ? cg[1] : cg[0]; v23 = (r_c & 1) ? cg[3] : cg[2];
            pre[1] = (r_c & 2) ? v23 : v01;
            cg = s2; v01 = (r_c & 1) ? cg[1] : cg[0]; v23 = (r_c & 1) ? cg[3] : cg[2];
            pre[2] = (r_c & 2) ? v23 : v01;
            cg = s3; v01 = (r_c & 1) ? cg[1] : cg[0]; v23 = (r_c & 1) ? cg[3] : cg[2];
            pre[3] = (r_c & 2) ? v23 : v01;
        }
        const float fi = fast_sig(pre[0]);
        const float ff = fast_sig(pre[1]);
        const float fo = fast_sig(pre[2]);
        const float fz = fast_tanh(pre[3]);
        cst = fi * fz + ff * cst;
        const float h = fo * fast_tanh(cst);
        accum += m * h;
        msum  += m;
        if (l16 < 8) hS[(s + 1) & 1][j] = (_Float16)h;
        __syncthreads();
    }
#undef MFALL
#undef MFLDS
#undef DECLF
#undef LOADF

    if (l16 < 8) out[b * 256 + j] = accum / msum;
}

extern "C" void kernel_launch(void* const* d_in, const int* in_sizes, int n_in,
                              void* d_out, int out_size, void* d_ws, size_t ws_size,
                              hipStream_t stream) {
    const float* X    = (const float*)d_in[0];
    const float* mask = (const float*)d_in[1];
    const float* Wi   = (const float*)d_in[2];
    const float* bi   = (const float*)d_in[3];
    const float* Wf   = (const float*)d_in[4];
    const float* bf   = (const float*)d_in[5];
    const float* Wo   = (const float*)d_in[6];
    const float* bo   = (const float*)d_in[7];
    const float* Wz   = (const float*)d_in[8];
    const float* bz   = (const float*)d_in[9];
    float* out = (float*)d_out;

    char* ws = (char*)d_ws;
    _Float16* G2  = (_Float16*)ws;                                   // 268,435,456 B
    _Float16* W4T = (_Float16*)(ws + (size_t)B_ * S_ * 1024 * 2);    //     458,752 B
    _Float16* WhT = (_Float16*)(ws + (size_t)B_ * S_ * 1024 * 2 + (size_t)1024 * 224 * 2);

    hipLaunchKernelGGL(prep,     dim3(1024), dim3(256), 0, stream, Wi, Wf, Wo, Wz, W4T, WhT);
    hipLaunchKernelGGL(gemm_x,   dim3(8192), dim3(256), 0, stream, X, W4T, bi, bf, bo, bz, G2);
    hipLaunchKernelGGL(lstm_rec, dim3(B_),   dim3(512), 0, stream, G2, WhT, mask, out);
}

// Round 7
// 1277.660 us; speedup vs baseline: 3.9000x; 1.1823x over previous
//
#include <hip/hip_runtime.h>
#include <hip/hip_fp16.h>

#define B_ 256
#define S_ 512
#define D_ 200
#define H_ 256

typedef _Float16 half2_t __attribute__((ext_vector_type(2)));
typedef _Float16 half4_t __attribute__((ext_vector_type(4)));
typedef _Float16 half8_t __attribute__((ext_vector_type(8)));
typedef float    floatx4 __attribute__((ext_vector_type(4)));

__device__ __forceinline__ float fast_sig(float x) {
    return 1.f / (1.f + __expf(-x));
}
__device__ __forceinline__ float fast_tanh(float x) {
    x = fminf(15.f, fmaxf(-15.f, x));
    float e = __expf(2.f * x);
    return (e - 1.f) / (e + 1.f);
}

// ---------------------------------------------------------------------------
// prep: build fp16 weight layouts in workspace.
//   W4T [1024][224]: W4T[n][k] = Wg[k][j] (x-part rows 0..199, zero-padded)
//   WhT [1024][256]: WhT[n][k] = Wg[200+k][j] (h-part), n = g*256+j
// ---------------------------------------------------------------------------
__global__ void prep(const float* __restrict__ Wi, const float* __restrict__ Wf,
                     const float* __restrict__ Wo, const float* __restrict__ Wz,
                     _Float16* __restrict__ W4T, _Float16* __restrict__ WhT) {
    const int n = blockIdx.x;      // 0..1023
    const int t = threadIdx.x;     // 0..255
    const int g = n >> 8, j = n & 255;
    const float* Wg = (g == 0) ? Wi : (g == 1) ? Wf : (g == 2) ? Wo : Wz;
    if (t < 224)
        W4T[(size_t)n * 224 + t] = (t < D_) ? (_Float16)Wg[t * 256 + j] : (_Float16)0.f;
    WhT[(size_t)n * 256 + t] = (_Float16)Wg[(D_ + t) * 256 + j];
}

// ---------------------------------------------------------------------------
// gemm_x: G[m][n] = sum_k X[m][k]*W4T[n][k] + bias[n]   (plain layout,
// coalesced stores: consecutive l16 -> consecutive gcol).
// ---------------------------------------------------------------------------
__global__ __launch_bounds__(256) void gemm_x(const float* __restrict__ X,
                                              const _Float16* __restrict__ W4T,
                                              const float* __restrict__ bi,
                                              const float* __restrict__ bfg,
                                              const float* __restrict__ bo,
                                              const float* __restrict__ bz,
                                              _Float16* __restrict__ G) {
    __shared__ __align__(16) _Float16 As[128][40];
    __shared__ __align__(16) _Float16 Bs[128][40];

    const int mt = blockIdx.x >> 3;
    const int nt = blockIdx.x & 7;
    const int m0 = mt * 128, n0 = nt * 128;
    const int tid  = threadIdx.x;
    const int lane = tid & 63, wave = tid >> 6;
    const int quad = lane >> 4, l16 = lane & 15;
    const int mq = (wave & 1) * 64, nq = (wave >> 1) * 64;

    floatx4 acc[4][4];
#pragma unroll
    for (int i = 0; i < 4; ++i)
#pragma unroll
        for (int j = 0; j < 4; ++j) acc[i][j] = (floatx4){0.f, 0.f, 0.f, 0.f};

    const int srow = tid >> 1;
    const int koff = (tid & 1) * 16;

    for (int kt = 0; kt < 7; ++kt) {
        const int k0 = kt * 32;
        {
            const int m = m0 + srow;
            const float* xr = X + (size_t)m * D_ + (k0 + koff);
            half8_t v0, v1;
            if (m < B_ * S_ - 1) {
                const floatx4* xp = (const floatx4*)xr;
                floatx4 f0 = xp[0], f1 = xp[1], f2 = xp[2], f3 = xp[3];
#pragma unroll
                for (int i = 0; i < 4; ++i) {
                    v0[i]     = (_Float16)f0[i];
                    v0[4 + i] = (_Float16)f1[i];
                    v1[i]     = (_Float16)f2[i];
                    v1[4 + i] = (_Float16)f3[i];
                }
            } else {
#pragma unroll
                for (int i = 0; i < 8; ++i) {
                    int k = k0 + koff + i;
                    v0[i] = (k < D_) ? (_Float16)xr[i] : (_Float16)0.f;
                }
#pragma unroll
                for (int i = 0; i < 8; ++i) {
                    int k = k0 + koff + 8 + i;
                    v1[i] = (k < D_) ? (_Float16)xr[8 + i] : (_Float16)0.f;
                }
            }
            *(half8_t*)&As[srow][koff]     = v0;
            *(half8_t*)&As[srow][koff + 8] = v1;
        }
        {
            const _Float16* wr = W4T + (size_t)(n0 + srow) * 224 + (k0 + koff);
            const half8_t* wp = (const half8_t*)wr;
            *(half8_t*)&Bs[srow][koff]     = wp[0];
            *(half8_t*)&Bs[srow][koff + 8] = wp[1];
        }
        __syncthreads();

        half8_t af[4], bf[4];
#pragma unroll
        for (int i = 0; i < 4; ++i) af[i] = *(const half8_t*)&As[mq + i * 16 + l16][quad * 8];
#pragma unroll
        for (int i = 0; i < 4; ++i) bf[i] = *(const half8_t*)&Bs[nq + i * 16 + l16][quad * 8];
#pragma unroll
        for (int mi = 0; mi < 4; ++mi)
#pragma unroll
            for (int ni = 0; ni < 4; ++ni)
                acc[mi][ni] = __builtin_amdgcn_mfma_f32_16x16x32_f16(af[mi], bf[ni], acc[mi][ni], 0, 0, 0);
        __syncthreads();
    }

    // ---- epilogue: plain coalesced stores, bias folded ----
#pragma unroll
    for (int ni = 0; ni < 4; ++ni) {
        const int gcol = n0 + nq + ni * 16 + l16;
        const int g = gcol >> 8, j = gcol & 255;
        const float bv = ((g == 0) ? bi : (g == 1) ? bfg : (g == 2) ? bo : bz)[j];
#pragma unroll
        for (int mi = 0; mi < 4; ++mi)
#pragma unroll
            for (int r = 0; r < 4; ++r) {
                const int grow = m0 + mq + mi * 16 + quad * 4 + r;
                G[(size_t)grow * 1024 + gcol] = (_Float16)(acc[mi][ni][r] + bv);
            }
    }
}

// ---------------------------------------------------------------------------
// lstm_rec: one workgroup (512 threads = 8 waves) per batch row.
// MFMA recurrence (validated in rounds 5/6):
//   A k in [0,192): 48 NAMED pinned half8 vars (192 regs).
//   A k in [192,256): LDS (128 KB), fragment order, lane-contiguous b128.
//   B: h broadcast, quad-uniform ds_read (issued FIRST each step).
//   C init: plain-layout G gather (8 x 8B same-addr-per-quad loads,
//   prefetched one step ahead; bias already folded by gemm_x).
// ---------------------------------------------------------------------------
__global__ __launch_bounds__(512, 2) void lstm_rec(
    const _Float16* __restrict__ G,     // [B][S][1024] plain, bias folded
    const _Float16* __restrict__ WhT,   // [1024][256] fp16
    const float* __restrict__ mask,     // [B][S] fp32
    float* __restrict__ out)            // [B][256] fp32
{
    __shared__ __align__(16) half8_t  WLfrag[8192];   // 128 KB
    __shared__ __align__(16) _Float16 hS[2][256];     // 1 KB

    const int b    = blockIdx.x;
    const int t    = threadIdx.x;   // 0..511
    const int w    = t >> 6;        // wave 0..7
    const int lane = t & 63;
    const int l16  = lane & 15, quad = lane >> 4;

    // ---- stage LDS A-fragments (k in [192,256)) in fragment order ----
#pragma unroll
    for (int mi = 0; mi < 8; ++mi) {
        const int gcol = ((mi & 3) << 8) + (2 * w + (mi >> 2)) * 16 + l16;
        const half8_t* src = (const half8_t*)(WhT + (size_t)gcol * 256);
        WLfrag[((w * 8 + mi) * 2 + 0) * 64 + lane] = src[6 * 4 + quad];
        WLfrag[((w * 8 + mi) * 2 + 1) * 64 + lane] = src[7 * 4 + quad];
    }

    // ---- register A-fragments: k in [0,192), 48 named pinned half8 ----
#define DECLF(mi) half8_t F##mi##_0, F##mi##_1, F##mi##_2, F##mi##_3, F##mi##_4, F##mi##_5
#define LOADF(mi) do {                                                        \
        const int gcol = ((mi & 3) << 8) + (2 * w + ((mi) >> 2)) * 16 + l16;  \
        const half8_t* p = (const half8_t*)(WhT + (size_t)gcol * 256);        \
        F##mi##_0 = p[0 * 4 + quad]; F##mi##_1 = p[1 * 4 + quad];             \
        F##mi##_2 = p[2 * 4 + quad]; F##mi##_3 = p[3 * 4 + quad];             \
        F##mi##_4 = p[4 * 4 + quad]; F##mi##_5 = p[5 * 4 + quad];             \
        asm volatile("" : "+v"(F##mi##_0), "+v"(F##mi##_1), "+v"(F##mi##_2),  \
                          "+v"(F##mi##_3), "+v"(F##mi##_4), "+v"(F##mi##_5)); \
    } while (0)
    DECLF(0); DECLF(1); DECLF(2); DECLF(3); DECLF(4); DECLF(5); DECLF(6); DECLF(7);
    LOADF(0); LOADF(1); LOADF(2); LOADF(3); LOADF(4); LOADF(5); LOADF(6); LOADF(7);

    if (t < 256) hS[0][t] = (_Float16)0.f;

    const int jbh_c = (l16 >> 2) & 1;
    const int r_c   = l16 & 3;
    const int j     = 32 * w + jbh_c * 16 + quad * 4 + r_c;

    float cst = 0.f, accum = 0.f, msum = 0.f;
    const float* mb = mask + (size_t)b * S_;

    // G gather base for this (b, w, quad); per-mi offsets are immediates.
    const _Float16* Gbase = G + ((size_t)b << 19) + 32 * w + quad * 4;

    half4_t N0, N1, N2, N3, N4, N5, N6, N7;
#define GLOAD(sidx) do {                                                      \
        const _Float16* gp = Gbase + ((size_t)(sidx) << 10);                  \
        N0 = *(const half4_t*)(gp + 0);   N1 = *(const half4_t*)(gp + 256);   \
        N2 = *(const half4_t*)(gp + 512); N3 = *(const half4_t*)(gp + 768);   \
        N4 = *(const half4_t*)(gp + 16);  N5 = *(const half4_t*)(gp + 272);   \
        N6 = *(const half4_t*)(gp + 528); N7 = *(const half4_t*)(gp + 784);   \
    } while (0)

    GLOAD(0);
    __syncthreads();

#define MFALL(kt, Bv)                                                          \
    C0 = __builtin_amdgcn_mfma_f32_16x16x32_f16(F0_##kt, Bv, C0, 0, 0, 0);     \
    C1 = __builtin_amdgcn_mfma_f32_16x16x32_f16(F1_##kt, Bv, C1, 0, 0, 0);     \
    C2 = __builtin_amdgcn_mfma_f32_16x16x32_f16(F2_##kt, Bv, C2, 0, 0, 0);     \
    C3 = __builtin_amdgcn_mfma_f32_16x16x32_f16(F3_##kt, Bv, C3, 0, 0, 0);     \
    C4 = __builtin_amdgcn_mfma_f32_16x16x32_f16(F4_##kt, Bv, C4, 0, 0, 0);     \
    C5 = __builtin_amdgcn_mfma_f32_16x16x32_f16(F5_##kt, Bv, C5, 0, 0, 0);     \
    C6 = __builtin_amdgcn_mfma_f32_16x16x32_f16(F6_##kt, Bv, C6, 0, 0, 0);     \
    C7 = __builtin_amdgcn_mfma_f32_16x16x32_f16(F7_##kt, Bv, C7, 0, 0, 0)

#define MFLDS(ktL, Bv)                                                         \
    C0 = __builtin_amdgcn_mfma_f32_16x16x32_f16(WLfrag[((w*8+0)*2+(ktL))*64+lane], Bv, C0, 0, 0, 0); \
    C1 = __builtin_amdgcn_mfma_f32_16x16x32_f16(WLfrag[((w*8+1)*2+(ktL))*64+lane], Bv, C1, 0, 0, 0); \
    C2 = __builtin_amdgcn_mfma_f32_16x16x32_f16(WLfrag[((w*8+2)*2+(ktL))*64+lane], Bv, C2, 0, 0, 0); \
    C3 = __builtin_amdgcn_mfma_f32_16x16x32_f16(WLfrag[((w*8+3)*2+(ktL))*64+lane], Bv, C3, 0, 0, 0); \
    C4 = __builtin_amdgcn_mfma_f32_16x16x32_f16(WLfrag[((w*8+4)*2+(ktL))*64+lane], Bv, C4, 0, 0, 0); \
    C5 = __builtin_amdgcn_mfma_f32_16x16x32_f16(WLfrag[((w*8+5)*2+(ktL))*64+lane], Bv, C5, 0, 0, 0); \
    C6 = __builtin_amdgcn_mfma_f32_16x16x32_f16(WLfrag[((w*8+6)*2+(ktL))*64+lane], Bv, C6, 0, 0, 0); \
    C7 = __builtin_amdgcn_mfma_f32_16x16x32_f16(WLfrag[((w*8+7)*2+(ktL))*64+lane], Bv, C7, 0, 0, 0)

    for (int s = 0; s < S_; ++s) {
        const float m = mb[s];
        const _Float16* hb = hS[s & 1];

        // 1) issue B ds_reads first (h is fresh past the barrier)
        half8_t Bv0 = *(const half8_t*)(hb + 0 * 32 + quad * 8);
        half8_t Bv1 = *(const half8_t*)(hb + 1 * 32 + quad * 8);
        half8_t Bv2 = *(const half8_t*)(hb + 2 * 32 + quad * 8);
        half8_t Bv3 = *(const half8_t*)(hb + 3 * 32 + quad * 8);

        // 2) C init from prefetched G gather (overlaps the LDS latency)
        floatx4 C0, C1, C2, C3, C4, C5, C6, C7;
#pragma unroll
        for (int k = 0; k < 4; ++k) {
            C0[k] = (float)N0[k]; C1[k] = (float)N1[k];
            C2[k] = (float)N2[k]; C3[k] = (float)N3[k];
            C4[k] = (float)N4[k]; C5[k] = (float)N5[k];
            C6[k] = (float)N6[k]; C7[k] = (float)N7[k];
        }
        // 3) prefetch next step's G (regs free after the cvts)
        GLOAD((s < S_ - 1) ? s + 1 : s);

        // 4) MFMA burst
        MFALL(0, Bv0);
        half8_t Bv4 = *(const half8_t*)(hb + 4 * 32 + quad * 8);
        half8_t Bv5 = *(const half8_t*)(hb + 5 * 32 + quad * 8);
        MFALL(1, Bv1);
        half8_t Bv6 = *(const half8_t*)(hb + 6 * 32 + quad * 8);
        half8_t Bv7 = *(const half8_t*)(hb + 7 * 32 + quad * 8);
        MFALL(2, Bv2);
        MFALL(3, Bv3);
        MFLDS(0, Bv6);
        MFLDS(1, Bv7);
        MFALL(4, Bv4);
        MFALL(5, Bv5);

        // 5) gate select: pre_g = C[jbh_c*4 + g][r_c]
        floatx4 s0 = jbh_c ? C4 : C0;
        floatx4 s1 = jbh_c ? C5 : C1;
        floatx4 s2 = jbh_c ? C6 : C2;
        floatx4 s3 = jbh_c ? C7 : C3;
        float pre0, pre1, pre2, pre3;
        {
            float v01 = (r_c & 1) ? s0[1] : s0[0], v23 = (r_c & 1) ? s0[3] : s0[2];
            pre0 = (r_c & 2) ? v23 : v01;
            v01 = (r_c & 1) ? s1[1] : s1[0]; v23 = (r_c & 1) ? s1[3] : s1[2];
            pre1 = (r_c & 2) ? v23 : v01;
            v01 = (r_c & 1) ? s2[1] : s2[0]; v23 = (r_c & 1) ? s2[3] : s2[2];
            pre2 = (r_c & 2) ? v23 : v01;
            v01 = (r_c & 1) ? s3[1] : s3[0]; v23 = (r_c & 1) ? s3[3] : s3[2];
            pre3 = (r_c & 2) ? v23 : v01;
        }
        const float fi = fast_sig(pre0);
        const float ff = fast_sig(pre1);
        const float fo = fast_sig(pre2);
        const float fz = fast_tanh(pre3);
        cst = fi * fz + ff * cst;
        const float h = fo * fast_tanh(cst);
        accum += m * h;
        msum  += m;
        if (l16 < 8) hS[(s + 1) & 1][j] = (_Float16)h;
        __syncthreads();
    }
#undef MFALL
#undef MFLDS
#undef DECLF
#undef LOADF
#undef GLOAD

    if (l16 < 8) out[b * 256 + j] = accum / msum;
}

extern "C" void kernel_launch(void* const* d_in, const int* in_sizes, int n_in,
                              void* d_out, int out_size, void* d_ws, size_t ws_size,
                              hipStream_t stream) {
    const float* X    = (const float*)d_in[0];
    const float* mask = (const float*)d_in[1];
    const float* Wi   = (const float*)d_in[2];
    const float* bi   = (const float*)d_in[3];
    const float* Wf   = (const float*)d_in[4];
    const float* bf   = (const float*)d_in[5];
    const float* Wo   = (const float*)d_in[6];
    const float* bo   = (const float*)d_in[7];
    const float* Wz   = (const float*)d_in[8];
    const float* bz   = (const float*)d_in[9];
    float* out = (float*)d_out;

    char* ws = (char*)d_ws;
    _Float16* G   = (_Float16*)ws;                                   // 268,435,456 B
    _Float16* W4T = (_Float16*)(ws + (size_t)B_ * S_ * 1024 * 2);    //     458,752 B
    _Float16* WhT = (_Float16*)(ws + (size_t)B_ * S_ * 1024 * 2 + (size_t)1024 * 224 * 2);

    hipLaunchKernelGGL(prep,     dim3(1024), dim3(256), 0, stream, Wi, Wf, Wo, Wz, W4T, WhT);
    hipLaunchKernelGGL(gemm_x,   dim3(8192), dim3(256), 0, stream, X, W4T, bi, bf, bo, bz, G);
    hipLaunchKernelGGL(lstm_rec, dim3(B_),   dim3(512), 0, stream, G, WhT, mask, out);
}